// Round 4
// baseline (84.673 us; speedup 1.0000x reference)
//
#include <hip/hip_runtime.h>

#define S_LEN 8192
#define DIM   64
#define WIN   64
#define QB    32            // queries per block (4 waves x 8 queries)
#define ROWS  160           // QB + 2*WIN rows staged
#define C0ROWS 80           // rows in chunk 0 (pipelined staging)
#define JCOUNT 136          // rows per wave: 8 + 2*WIN
#define NXCD  8

// Butterfly add over 8-lane groups, pure VALU (DPP), no DS pipe.
// 0xB1 = quad_perm(1,0,3,2) -> xor1; 0x4E = quad_perm(2,3,0,1) -> xor2;
// 0x141 = row_half_mirror -> xor7 (crosses quads within the octet)
template<int CTRL>
__device__ __forceinline__ float dpp_add(float v) {
    int s = __builtin_amdgcn_update_dpp(0, __float_as_int(v), CTRL, 0xF, 0xF, true);
    return v + __int_as_float(s);
}

__global__ __launch_bounds__(256, 2)
void swa_fwd(const float* __restrict__ qg,
             const float* __restrict__ kg,
             const float* __restrict__ vg,
             float* __restrict__ outg) {
    __shared__ float smem[2 * ROWS * DIM];   // 80 KiB: ks | vs -> 2 blocks/CU
    float* ks = smem;
    float* vs = smem + ROWS * DIM;

    // XCD-aware swizzle: consecutive logical blocks (sharing window rows)
    // land on the same XCD's L2. grid is a multiple of 8 -> bijective.
    const int nwg = gridDim.x;
    const int cpx = nwg / NXCD;
    const int lb  = (blockIdx.x % NXCD) * cpx + blockIdx.x / NXCD;

    const int nqb = S_LEN / QB;
    const int b   = lb / nqb;
    const int s0  = (lb % nqb) * QB;
    const int tid = threadIdx.x;
    const int c0  = s0 - WIN;            // first staged row (may be <0)

    // ---- stage chunk 0 (rows [0,80)): 1280 f4/tensor, 5 f4/thread, coalesced.
    // OOB rows: clamp address (garbage is finite and masked to e=0 later).
    float4 kbuf[5], vbuf[5];
    #pragma unroll
    for (int t = 0; t < 5; ++t) {
        int f4 = tid + t * 256;
        int gr = c0 + (f4 >> 4);
        gr = gr < 0 ? 0 : (gr > S_LEN - 1 ? S_LEN - 1 : gr);
        int base = (b * S_LEN + gr) * DIM + ((f4 & 15) << 2);
        kbuf[t] = *reinterpret_cast<const float4*>(kg + base);
        vbuf[t] = *reinterpret_cast<const float4*>(vg + base);
    }
    #pragma unroll
    for (int t = 0; t < 5; ++t) {
        int f4 = tid + t * 256;
        reinterpret_cast<float4*>(ks)[f4] = kbuf[t];
        reinterpret_cast<float4*>(vs)[f4] = vbuf[t];
    }

    // ---- issue chunk-1 global loads NOW (rows [80,160)); the vmcnt waits
    // sink to the ds_writes after compute0 -> HBM latency hides under compute.
    #pragma unroll
    for (int t = 0; t < 5; ++t) {
        int f4 = 1280 + tid + t * 256;
        int gr = c0 + (f4 >> 4);
        gr = gr < 0 ? 0 : (gr > S_LEN - 1 ? S_LEN - 1 : gr);
        int base = (b * S_LEN + gr) * DIM + ((f4 & 15) << 2);
        kbuf[t] = *reinterpret_cast<const float4*>(kg + base);
        vbuf[t] = *reinterpret_cast<const float4*>(vg + base);
    }

    const int wv   = tid >> 6;           // wave 0..3 -> queries s0+8*wv..+7
    const int lane = tid & 63;
    const int g    = lane >> 3;          // group 0..7 -> one query
    const int sub  = lane & 7;           // dim slice 8*sub..8*sub+7
    const int q    = s0 + 8 * wv + g;

    // q fragment, pre-scaled by D^-0.5 * log2(e): score->prob is one v_exp_f32
    const float qscale = 0.125f * 1.44269504088896340736f;
    const float* qp = qg + (b * S_LEN + q) * DIM + 8 * sub;
    float4 q0 = *reinterpret_cast<const float4*>(qp);
    float4 q1 = *reinterpret_cast<const float4*>(qp + 4);
    q0.x *= qscale; q0.y *= qscale; q0.z *= qscale; q0.w *= qscale;
    q1.x *= qscale; q1.y *= qscale; q1.z *= qscale; q1.w *= qscale;

    // valid j range: r(j) = c0 + 8*wv + j must lie in [q-WIN, q+WIN] ∩ [0,S)
    const int jlo = max(g, WIN - s0 - 8 * wv);
    const int jhi = min(g + 2 * WIN, S_LEN - 1 - s0 + WIN - 8 * wv);

    const float* kbase = ks + (8 * wv) * DIM + 8 * sub;
    const float* vbase = vs + (8 * wv) * DIM + 8 * sub;

    float l = 0.f;
    float o[8] = {0.f, 0.f, 0.f, 0.f, 0.f, 0.f, 0.f, 0.f};

    auto body = [&](int j) {
        const float* kr = kbase + j * DIM;
        const float* vr = vbase + j * DIM;
        float4 k0 = *reinterpret_cast<const float4*>(kr);
        float4 k1 = *reinterpret_cast<const float4*>(kr + 4);
        float4 v0 = *reinterpret_cast<const float4*>(vr);
        float4 v1 = *reinterpret_cast<const float4*>(vr + 4);

        float p = q0.x * k0.x + q0.y * k0.y + q0.z * k0.z + q0.w * k0.w
                + q1.x * k1.x + q1.y * k1.y + q1.z * k1.z + q1.w * k1.w;
        p = dpp_add<0xB1>(p);
        p = dpp_add<0x4E>(p);
        p = dpp_add<0x141>(p);

        float e = (j >= jlo && j <= jhi) ? __builtin_amdgcn_exp2f(p) : 0.f;
        l += e;
        o[0] += e * v0.x; o[1] += e * v0.y; o[2] += e * v0.z; o[3] += e * v0.w;
        o[4] += e * v1.x; o[5] += e * v1.y; o[6] += e * v1.z; o[7] += e * v1.w;
    };

    __syncthreads();                     // chunk-0 LDS visible

    // ---- compute chunk-0 rows: row = 8*wv + j < 80  ->  j < 80 - 8*wv
    const int jsplit = C0ROWS - 8 * wv;  // 80, 72, 64, 56
    #pragma unroll 4
    for (int j = 0; j < jsplit; ++j) body(j);

    // ---- land chunk 1 (LDS rows [80,160): disjoint from all chunk-0 reads,
    // so no barrier needed before these writes)
    #pragma unroll
    for (int t = 0; t < 5; ++t) {
        int f4 = 1280 + tid + t * 256;
        reinterpret_cast<float4*>(ks)[f4] = kbuf[t];
        reinterpret_cast<float4*>(vs)[f4] = vbuf[t];
    }
    __syncthreads();                     // chunk-1 LDS visible

    #pragma unroll 4
    for (int j = jsplit; j < JCOUNT; ++j) body(j);

    const float inv = 1.0f / l;
    float* op = outg + (b * S_LEN + q) * DIM + 8 * sub;
    *reinterpret_cast<float4*>(op)     = make_float4(o[0]*inv, o[1]*inv, o[2]*inv, o[3]*inv);
    *reinterpret_cast<float4*>(op + 4) = make_float4(o[4]*inv, o[5]*inv, o[6]*inv, o[7]*inv);
}

extern "C" void kernel_launch(void* const* d_in, const int* in_sizes, int n_in,
                              void* d_out, int out_size, void* d_ws, size_t ws_size,
                              hipStream_t stream) {
    const float* q = (const float*)d_in[0];
    const float* k = (const float*)d_in[1];
    const float* v = (const float*)d_in[2];
    float* out = (float*)d_out;
    int B = in_sizes[0] / (S_LEN * DIM);
    dim3 grid(B * (S_LEN / QB));          // 512 blocks for B=2
    swa_fwd<<<grid, 256, 0, stream>>>(q, k, v, out);
}

// Round 5
// 81.699 us; speedup vs baseline: 1.0364x; 1.0364x over previous
//
#include <hip/hip_runtime.h>

#define S_LEN 8192
#define DIM   64
#define WIN   64
#define QB    32            // queries per block (4 waves x 8 queries)
#define ROWS  160           // QB + 2*WIN rows staged
#define C0ROWS 80           // rows in chunk 0
#define JCOUNT 136          // rows per wave: 8 + 2*WIN
#define NXCD  8

// Butterfly add over 8-lane groups, pure VALU (DPP), no DS pipe.
// 0xB1 = quad_perm(1,0,3,2) -> xor1; 0x4E = quad_perm(2,3,0,1) -> xor2;
// 0x141 = row_half_mirror -> completes the 8-lane sum
template<int CTRL>
__device__ __forceinline__ float dpp_add(float v) {
    int s = __builtin_amdgcn_update_dpp(0, __float_as_int(v), CTRL, 0xF, 0xF, true);
    return v + __int_as_float(s);
}

// async global->LDS, 16B per lane; LDS dest is wave-uniform base + lane*16
__device__ __forceinline__ void gload16(const float* g, float* l) {
    __builtin_amdgcn_global_load_lds(
        (const __attribute__((address_space(1))) unsigned int*)g,
        (__attribute__((address_space(3))) unsigned int*)l,
        16, 0, 0);
}

__global__ __launch_bounds__(256, 2)
void swa_fwd(const float* __restrict__ qg,
             const float* __restrict__ kg,
             const float* __restrict__ vg,
             float* __restrict__ outg) {
    __shared__ __align__(16) float smem[2 * ROWS * DIM];  // 80 KiB -> 2 blocks/CU
    float* ks = smem;
    float* vs = smem + ROWS * DIM;

    // XCD-aware swizzle: consecutive logical blocks (sharing window rows)
    // land on the same XCD's L2. grid is a multiple of 8 -> bijective.
    const int nwg = gridDim.x;
    const int cpx = nwg / NXCD;
    const int lb  = (blockIdx.x % NXCD) * cpx + blockIdx.x / NXCD;

    const int nqb = S_LEN / QB;
    const int b   = lb / nqb;
    const int s0  = (lb % nqb) * QB;
    const int tid = threadIdx.x;
    const int c0  = s0 - WIN;            // first staged row (may be <0)

    const int wv   = tid >> 6;           // wave 0..3 -> queries s0+8*wv..+7
    const int lane = tid & 63;
    const int g    = lane >> 3;          // group 0..7 -> one query
    const int sub  = lane & 7;           // dim slice 8*sub..8*sub+7
    const int q    = s0 + 8 * wv + g;

    // ---- q fragment: issue FIRST so its vmcnt entries are oldest
    const float* qp = qg + (b * S_LEN + q) * DIM + 8 * sub;
    float4 q0 = *reinterpret_cast<const float4*>(qp);
    float4 q1 = *reinterpret_cast<const float4*>(qp + 4);
    __builtin_amdgcn_sched_barrier(0);   // pin q loads ahead of staging

    // ---- chunk 0 (LDS rows [0,80)): 10 gload_lds/thread, linear lane layout.
    // OOB rows: clamp source address (finite garbage, masked to e=0 later).
    #pragma unroll
    for (int t = 0; t < 5; ++t) {
        int f4 = tid + t * 256;          // 0..1279
        int gr = c0 + (f4 >> 4);
        gr = gr < 0 ? 0 : (gr > S_LEN - 1 ? S_LEN - 1 : gr);
        int base = (b * S_LEN + gr) * DIM + ((f4 & 15) << 2);
        int lbase = (t * 256 + wv * 64) << 2;     // wave-uniform float index
        gload16(kg + base, ks + lbase);
        gload16(vg + base, vs + lbase);
    }
    // ---- chunk 1 (LDS rows [80,160)): issued now, lands under compute-0
    #pragma unroll
    for (int t = 0; t < 5; ++t) {
        int f4 = 1280 + tid + t * 256;   // 1280..2559
        int gr = c0 + (f4 >> 4);
        gr = gr < 0 ? 0 : (gr > S_LEN - 1 ? S_LEN - 1 : gr);
        int base = (b * S_LEN + gr) * DIM + ((f4 & 15) << 2);
        int lbase = (1280 + t * 256 + wv * 64) << 2;
        gload16(kg + base, ks + lbase);
        gload16(vg + base, vs + lbase);
    }

    // q pre-scaled by D^-0.5 * log2(e): score->prob is one v_exp_f32
    const float qscale = 0.125f * 1.44269504088896340736f;
    q0.x *= qscale; q0.y *= qscale; q0.z *= qscale; q0.w *= qscale;
    q1.x *= qscale; q1.y *= qscale; q1.z *= qscale; q1.w *= qscale;

    // valid j range: r(j) = c0 + 8*wv + j must lie in [q-WIN, q+WIN] ∩ [0,S)
    const int jlo = max(g, WIN - s0 - 8 * wv);
    const int jhi = min(g + 2 * WIN, S_LEN - 1 - s0 + WIN - 8 * wv);

    const float* kbase = ks + (8 * wv) * DIM + 8 * sub;
    const float* vbase = vs + (8 * wv) * DIM + 8 * sub;

    float l = 0.f;
    float o[8] = {0.f, 0.f, 0.f, 0.f, 0.f, 0.f, 0.f, 0.f};

    auto body = [&](int j) {
        const float* kr = kbase + j * DIM;
        const float* vr = vbase + j * DIM;
        float4 k0 = *reinterpret_cast<const float4*>(kr);
        float4 k1 = *reinterpret_cast<const float4*>(kr + 4);
        float4 v0 = *reinterpret_cast<const float4*>(vr);
        float4 v1 = *reinterpret_cast<const float4*>(vr + 4);

        float p = q0.x * k0.x + q0.y * k0.y + q0.z * k0.z + q0.w * k0.w
                + q1.x * k1.x + q1.y * k1.y + q1.z * k1.z + q1.w * k1.w;
        p = dpp_add<0xB1>(p);
        p = dpp_add<0x4E>(p);
        p = dpp_add<0x141>(p);

        float e = ((unsigned)(j - jlo) <= (unsigned)(jhi - jlo))
                    ? __builtin_amdgcn_exp2f(p) : 0.f;
        l += e;
        o[0] += e * v0.x; o[1] += e * v0.y; o[2] += e * v0.z; o[3] += e * v0.w;
        o[4] += e * v1.x; o[5] += e * v1.y; o[6] += e * v1.z; o[7] += e * v1.w;
    };

    // ---- barrier 1: chunk-0 landed (own 10 youngest = chunk-1 may fly on)
    asm volatile("s_waitcnt vmcnt(10)" ::: "memory");
    __builtin_amdgcn_s_barrier();
    __builtin_amdgcn_sched_barrier(0);

    // compute chunk-0 rows: row = 8*wv + j < 80  ->  j < 80 - 8*wv
    const int jsplit = C0ROWS - 8 * wv;  // 80, 72, 64, 56
    #pragma unroll 4
    for (int j = 0; j < jsplit; ++j) body(j);

    // ---- barrier 2: chunk-1 landed everywhere
    asm volatile("s_waitcnt vmcnt(0)" ::: "memory");
    __builtin_amdgcn_s_barrier();
    __builtin_amdgcn_sched_barrier(0);

    #pragma unroll 4
    for (int j = jsplit; j < JCOUNT; ++j) body(j);

    const float inv = 1.0f / l;
    float* op = outg + (b * S_LEN + q) * DIM + 8 * sub;
    *reinterpret_cast<float4*>(op)     = make_float4(o[0]*inv, o[1]*inv, o[2]*inv, o[3]*inv);
    *reinterpret_cast<float4*>(op + 4) = make_float4(o[4]*inv, o[5]*inv, o[6]*inv, o[7]*inv);
}

extern "C" void kernel_launch(void* const* d_in, const int* in_sizes, int n_in,
                              void* d_out, int out_size, void* d_ws, size_t ws_size,
                              hipStream_t stream) {
    const float* q = (const float*)d_in[0];
    const float* k = (const float*)d_in[1];
    const float* v = (const float*)d_in[2];
    float* out = (float*)d_out;
    int B = in_sizes[0] / (S_LEN * DIM);
    dim3 grid(B * (S_LEN / QB));          // 512 blocks for B=2
    swa_fwd<<<grid, 256, 0, stream>>>(q, k, v, out);
}

// Round 6
// 81.592 us; speedup vs baseline: 1.0378x; 1.0013x over previous
//
#include <hip/hip_runtime.h>

#define S_LEN 8192
#define DIM   64
#define WIN   64
#define QB    32            // queries per block (all 4 waves share them)
#define ROWS  160           // QB + 2*WIN staged rows
#define RPW   40            // rows per wave (4-way key-split)
#define CSTRIDE 68          // combine row stride: 64 o + 1 l + pad
#define NXCD  8

// Butterfly add over 8-lane groups, pure VALU (DPP), no DS pipe.
// 0xB1=quad_perm xor1; 0x4E=quad_perm xor2; 0x141=row_half_mirror (xor7)
template<int CTRL>
__device__ __forceinline__ float dpp_add(float v) {
    int s = __builtin_amdgcn_update_dpp(0, __float_as_int(v), CTRL, 0xF, 0xF, true);
    return v + __int_as_float(s);
}

// async global->LDS, 16B/lane; LDS dest = wave-uniform base + lane*16
__device__ __forceinline__ void gload16(const float* g, float* l) {
    __builtin_amdgcn_global_load_lds(
        (const __attribute__((address_space(1))) unsigned int*)g,
        (__attribute__((address_space(3))) unsigned int*)l,
        16, 0, 0);
}

__global__ __launch_bounds__(256, 2)
void swa_fwd(const float* __restrict__ qg,
             const float* __restrict__ kg,
             const float* __restrict__ vg,
             float* __restrict__ outg) {
    __shared__ __align__(16) float smem[2 * ROWS * DIM];  // 80 KiB -> 2 blocks/CU
    float* ks = smem;
    float* vs = smem + ROWS * DIM;

    // XCD swizzle: neighbor logical blocks (sharing window rows) on same L2
    const int nwg = gridDim.x;
    const int cpx = nwg / NXCD;
    const int lb  = (blockIdx.x % NXCD) * cpx + blockIdx.x / NXCD;

    const int nqb  = S_LEN / QB;
    const int b    = lb / nqb;
    const int s0   = (lb % nqb) * QB;
    const int tid  = threadIdx.x;
    const int wv   = tid >> 6;          // wave: key-split slice [40wv, 40wv+40)
    const int lane = tid & 63;
    const int g    = lane >> 3;         // 8 groups/wave
    const int sub  = lane & 7;          // dim slice 8*sub..+7
    const int c0   = s0 - WIN;          // first staged row (may be <0)

    // ---- stage own 40-row slice: K and V, 10 gload16 each, coalesced 1KB/instr.
    // Wave reads ONLY rows it stages itself -> NO barrier before compute.
    // OOB rows: clamp source (finite garbage, masked to e=0 by vlo/vhi).
    #pragma unroll
    for (int t = 0; t < 10; ++t) {
        int f4 = wv * 640 + t * 64 + lane;      // f4 index in [wv*640, wv*640+640)
        int gr = c0 + (f4 >> 4);
        gr = gr < 0 ? 0 : (gr > S_LEN - 1 ? S_LEN - 1 : gr);
        int base  = (b * S_LEN + gr) * DIM + ((f4 & 15) << 2);
        int lbase = (wv * 2560 + t * 256);      // wave-uniform float offset
        gload16(kg + base, ks + lbase);
        gload16(vg + base, vs + lbase);
    }

    // ---- q fragments for this group's 4 queries (same for all 4 waves)
    const float qscale = 0.125f * 1.44269504088896340736f;
    float qreg[4][8];
    int vlo[4], vhi[4];
    #pragma unroll
    for (int jj = 0; jj < 4; ++jj) {
        int s = s0 + 4 * g + jj;
        vlo[jj] = (s - WIN < 0) ? 0 : (s - WIN);
        vhi[jj] = (s + WIN > S_LEN - 1) ? (S_LEN - 1) : (s + WIN);
        const float4* qp = reinterpret_cast<const float4*>(qg + (b * S_LEN + s) * DIM + 8 * sub);
        float4 a = qp[0], c = qp[1];
        qreg[jj][0] = a.x * qscale; qreg[jj][1] = a.y * qscale;
        qreg[jj][2] = a.z * qscale; qreg[jj][3] = a.w * qscale;
        qreg[jj][4] = c.x * qscale; qreg[jj][5] = c.y * qscale;
        qreg[jj][6] = c.z * qscale; qreg[jj][7] = c.w * qscale;
    }

    float l[4] = {0.f, 0.f, 0.f, 0.f};
    float o[4][8] = {};

    // own staged slice landed (also drains q loads; no cross-wave barrier!)
    asm volatile("s_waitcnt vmcnt(0)" ::: "memory");
    __builtin_amdgcn_sched_barrier(0);

    const float* kbase = ks + wv * (RPW * DIM) + 8 * sub;
    const float* vbase = vs + wv * (RPW * DIM) + 8 * sub;

    #pragma unroll 2
    for (int rr = 0; rr < RPW; ++rr) {
        const int r = c0 + wv * RPW + rr;
        const float* kr = kbase + rr * DIM;
        const float* vr = vbase + rr * DIM;
        float4 k0 = *reinterpret_cast<const float4*>(kr);
        float4 k1 = *reinterpret_cast<const float4*>(kr + 4);
        float4 v0 = *reinterpret_cast<const float4*>(vr);
        float4 v1 = *reinterpret_cast<const float4*>(vr + 4);

        float p[4];
        #pragma unroll
        for (int jj = 0; jj < 4; ++jj)
            p[jj] = qreg[jj][0]*k0.x + qreg[jj][1]*k0.y + qreg[jj][2]*k0.z + qreg[jj][3]*k0.w
                  + qreg[jj][4]*k1.x + qreg[jj][5]*k1.y + qreg[jj][6]*k1.z + qreg[jj][7]*k1.w;
        #pragma unroll
        for (int jj = 0; jj < 4; ++jj) p[jj] = dpp_add<0xB1>(p[jj]);
        #pragma unroll
        for (int jj = 0; jj < 4; ++jj) p[jj] = dpp_add<0x4E>(p[jj]);
        #pragma unroll
        for (int jj = 0; jj < 4; ++jj) p[jj] = dpp_add<0x141>(p[jj]);

        #pragma unroll
        for (int jj = 0; jj < 4; ++jj) {
            bool valid = (r >= vlo[jj]) && (r <= vhi[jj]);
            float e = valid ? __builtin_amdgcn_exp2f(p[jj]) : 0.f;
            l[jj] += e;
            o[jj][0] += e * v0.x; o[jj][1] += e * v0.y;
            o[jj][2] += e * v0.z; o[jj][3] += e * v0.w;
            o[jj][4] += e * v1.x; o[jj][5] += e * v1.y;
            o[jj][6] += e * v1.z; o[jj][7] += e * v1.w;
        }
    }

    // ---- combine across the 4 key-split waves via LDS (round-2-validated)
    __syncthreads();                    // everyone done reading K/V
    float* comb = smem;                 // [4 waves][32 q][CSTRIDE] = 34.8 KiB
    #pragma unroll
    for (int jj = 0; jj < 4; ++jj) {
        int qi = 4 * g + jj;
        float* dst = comb + (wv * QB + qi) * CSTRIDE + 8 * sub;
        *reinterpret_cast<float4*>(dst)     = make_float4(o[jj][0], o[jj][1], o[jj][2], o[jj][3]);
        *reinterpret_cast<float4*>(dst + 4) = make_float4(o[jj][4], o[jj][5], o[jj][6], o[jj][7]);
        if (sub == 0) comb[(wv * QB + qi) * CSTRIDE + 64] = l[jj];
    }
    __syncthreads();

    // thread t -> query t>>3, dims (t&7)*8 ..+8
    {
        int qi = tid >> 3;
        int ds = (tid & 7) * 8;
        float acc[8] = {};
        float denom = 0.f;
        #pragma unroll
        for (int w = 0; w < 4; ++w) {
            const float* src = comb + (w * QB + qi) * CSTRIDE;
            denom += src[64];
            float4 a = *reinterpret_cast<const float4*>(src + ds);
            float4 c = *reinterpret_cast<const float4*>(src + ds + 4);
            acc[0] += a.x; acc[1] += a.y; acc[2] += a.z; acc[3] += a.w;
            acc[4] += c.x; acc[5] += c.y; acc[6] += c.z; acc[7] += c.w;
        }
        float inv = 1.0f / denom;
        float* op = outg + (b * S_LEN + s0 + qi) * DIM + ds;
        *reinterpret_cast<float4*>(op)     = make_float4(acc[0]*inv, acc[1]*inv, acc[2]*inv, acc[3]*inv);
        *reinterpret_cast<float4*>(op + 4) = make_float4(acc[4]*inv, acc[5]*inv, acc[6]*inv, acc[7]*inv);
    }
}

extern "C" void kernel_launch(void* const* d_in, const int* in_sizes, int n_in,
                              void* d_out, int out_size, void* d_ws, size_t ws_size,
                              hipStream_t stream) {
    const float* q = (const float*)d_in[0];
    const float* k = (const float*)d_in[1];
    const float* v = (const float*)d_in[2];
    float* out = (float*)d_out;
    int B = in_sizes[0] / (S_LEN * DIM);
    dim3 grid(B * (S_LEN / QB));          // 512 blocks for B=2
    swa_fwd<<<grid, 256, 0, stream>>>(q, k, v, out);
}